// Round 16
// baseline (357.222 us; speedup 1.0000x reference)
//
#include <hip/hip_runtime.h>
#include <hip/hip_bf16.h>
#include <math.h>

#define NB 16
#define NS 4096
#define ND 1024
#define NM (NB * NS)

// workspace layout (float offsets)
#define WS_T       0                            // 16*1024
#define WS_SCORES  16384                        // 16*4096 (fallback path)
#define WS_WEIGHTS (WS_SCORES + NB * NS)        // 16*4096
#define WS_SHARED  (WS_WEIGHTS + NB * NS)       // 2MB: wbf16 (convw->scores); fallback: part overlay
#define WS_XBF16   (WS_SHARED + 524288)         // 67.1M ushorts (134 MB): xbf side-written by scores
#define WS_SPART   (WS_XBF16 + 33554432)        // 2MB: spart[8][65536] (scores->softmax) then part
#define WS_NEED    (((size_t)WS_SPART + 524288) * 4)

typedef short v8s __attribute__((ext_vector_type(8)));
typedef float v4f __attribute__((ext_vector_type(4)));
typedef unsigned short ushort;

#define G_AS __attribute__((address_space(1)))
#define L_AS __attribute__((address_space(3)))

__device__ __forceinline__ ushort f2bf(float f) {
    __hip_bfloat16 h = __float2bfloat16(f);
    return *reinterpret_cast<ushort*>(&h);
}

__device__ __forceinline__ float bf2f(ushort u) {
    return __uint_as_float(((unsigned)u) << 16);
}

__device__ __forceinline__ float fast_tanh(float x) {
    float e = __expf(2.0f * x);
    return 1.0f - 2.0f / (e + 1.0f);
}

// ---------------- kernel 0: W_in fp32 -> bf16 ----------------
__global__ __launch_bounds__(256) void convw_kernel(const float* __restrict__ W,
                                                    ushort* __restrict__ Wb) {
    int flat = blockIdx.x * 256 + threadIdx.x;
#pragma unroll
    for (int j = 0; j < 2; ++j) {
        int idx = flat + j * 131072;
        float4 v = ((const float4*)W)[idx];
        ushort4 o;
        o.x = f2bf(v.x); o.y = f2bf(v.y); o.z = f2bf(v.z); o.w = f2bf(v.w);
        ((ushort4*)Wb)[idx] = o;
    }
}

// ---------------- kernel 1: t[b][e] = b_in[e]+b_ctx[e]+context[b].W_ctx[e] ----------------
__global__ __launch_bounds__(256) void tvec_kernel(const float* __restrict__ context,
                                                   const float* __restrict__ W_ctx,
                                                   const float* __restrict__ b_in,
                                                   const float* __restrict__ b_ctx,
                                                   float* __restrict__ t) {
    __shared__ float ctx[ND];
    int b = blockIdx.y;
    int tid = threadIdx.x;
    for (int i = tid; i < ND; i += 256) ctx[i] = context[b * ND + i];
    __syncthreads();
    int e = blockIdx.x * 64 + (tid >> 2);
    int kq = tid & 3;
    const float4* wr = (const float4*)(W_ctx + (size_t)e * ND + kq * 256);
    const float4* cr = (const float4*)(ctx + kq * 256);
    float acc = 0.f;
#pragma unroll 4
    for (int k = 0; k < 64; ++k) {
        float4 w = wr[k];
        float4 c = cr[k];
        acc += c.x * w.x + c.y * w.y + c.z * w.z + c.w * w.w;
    }
    acc += __shfl_xor(acc, 1);
    acc += __shfl_xor(acc, 2);
    if (kq == 0) t[b * ND + e] = acc + b_in[e] + b_ctx[e];
}

// ================= FAST scores: 128x128xBK32, 4 blocks/CU, T14 reg-staged A + xbf side-write =================
// Round-15 structure verbatim, plus: ct==0 blocks (one per row-tile) store their cvt'd bf16 A-tiles
// to global xbf (134 MB total) so wsum can read bf16 instead of fp32 (halves its HBM).
// Stores are issued after each step's vmcnt wait; at the next wait they are the oldest ops,
// retired ~1 step earlier -> conservative, no correctness impact.
__global__ __launch_bounds__(256, 4) void scores_tile_kernel(const float* __restrict__ x,
                                                             const ushort* __restrict__ Wb,
                                                             const float* __restrict__ t,
                                                             const float* __restrict__ w_att,
                                                             float* __restrict__ spart,
                                                             ushort* __restrict__ xbf) {
    __shared__ ushort As[2][4096];   // 8 KB each: granule (row*4+kq)*8 ushorts
    __shared__ ushort Bs[2][4096];
    __shared__ float red[4][64];

    int tid = threadIdx.x;
    int o = blockIdx.x;              // 4096 blocks
    int rt = (o & 7) * 64 + (o >> 6);
    int ct = (o >> 3) & 7;
    int row0 = rt << 7;
    int e0 = ct << 7;
    int b = row0 >> 12;              // 128 | 4096
    bool ct0 = (ct == 0);            // this block side-writes xbf for its 128 rows

    int g0 = tid, g1 = tid + 256;
    const float* gxA0 = x + (size_t)(row0 + (tid >> 2)) * ND + (tid & 3) * 8;
    const float* gxA1 = gxA0 + (size_t)64 * ND;
    ushort* gxbA0 = xbf + (size_t)(row0 + (tid >> 2)) * ND + (tid & 3) * 8;
    ushort* gxbA1 = gxbA0 + (size_t)64 * ND;
    const ushort* gaB0 = Wb + (size_t)(e0 + (g0 >> 2)) * ND + (g0 & 3) * 8;
    const ushort* gaB1 = Wb + (size_t)(e0 + (g1 >> 2)) * ND + (g1 & 3) * 8;

    int w = tid >> 6, l = tid & 63;
    int l15 = l & 15, kq4 = l >> 4;
    int R = (w >> 1) * 64;
    int E = (w & 1) * 64;

    v4f acc[4][4];
#pragma unroll
    for (int i = 0; i < 4; ++i)
#pragma unroll
        for (int j = 0; j < 4; ++j) acc[i][j] = (v4f)(0.f);

    float4 ra[2][4];

#define ISSUE(KT, RS)                                                                               \
    {                                                                                               \
        ra[RS][0] = *(const float4*)(gxA0 + (KT) * 32);                                             \
        ra[RS][1] = *(const float4*)(gxA0 + (KT) * 32 + 4);                                         \
        ra[RS][2] = *(const float4*)(gxA1 + (KT) * 32);                                             \
        ra[RS][3] = *(const float4*)(gxA1 + (KT) * 32 + 4);                                         \
        __builtin_amdgcn_global_load_lds((const G_AS void*)(gaB0 + (KT) * 32),                      \
                                         (L_AS void*)&Bs[(KT) & 1][g0 * 8], 16, 0, 0);             \
        __builtin_amdgcn_global_load_lds((const G_AS void*)(gaB1 + (KT) * 32),                      \
                                         (L_AS void*)&Bs[(KT) & 1][g1 * 8], 16, 0, 0);             \
    }

#define WRITEA(RS, BUF, KT)                                                                         \
    {                                                                                               \
        v8s w0, w1;                                                                                 \
        w0[0] = (short)f2bf(ra[RS][0].x); w0[1] = (short)f2bf(ra[RS][0].y);                         \
        w0[2] = (short)f2bf(ra[RS][0].z); w0[3] = (short)f2bf(ra[RS][0].w);                         \
        w0[4] = (short)f2bf(ra[RS][1].x); w0[5] = (short)f2bf(ra[RS][1].y);                         \
        w0[6] = (short)f2bf(ra[RS][1].z); w0[7] = (short)f2bf(ra[RS][1].w);                         \
        w1[0] = (short)f2bf(ra[RS][2].x); w1[1] = (short)f2bf(ra[RS][2].y);                         \
        w1[2] = (short)f2bf(ra[RS][2].z); w1[3] = (short)f2bf(ra[RS][2].w);                         \
        w1[4] = (short)f2bf(ra[RS][3].x); w1[5] = (short)f2bf(ra[RS][3].y);                         \
        w1[6] = (short)f2bf(ra[RS][3].z); w1[7] = (short)f2bf(ra[RS][3].w);                         \
        *(v8s*)&As[BUF][g0 * 8] = w0;                                                               \
        *(v8s*)&As[BUF][g1 * 8] = w1;                                                               \
        if (ct0) {                                                                                  \
            *(v8s*)(gxbA0 + (KT) * 32) = w0;                                                        \
            *(v8s*)(gxbA1 + (KT) * 32) = w1;                                                        \
        }                                                                                           \
        asm volatile("s_waitcnt lgkmcnt(0)" ::: "memory");                                          \
    }

#define COMPUTE(BUF)                                                                          \
    {                                                                                         \
        v8s af[4], bf[4];                                                                     \
        _Pragma("unroll") for (int mf = 0; mf < 4; ++mf)                                      \
            af[mf] = *(const v8s*)&As[BUF][((R + mf * 16 + l15) * 4 + kq4) * 8];              \
        _Pragma("unroll") for (int nf = 0; nf < 4; ++nf)                                      \
            bf[nf] = *(const v8s*)&Bs[BUF][((E + nf * 16 + l15) * 4 + kq4) * 8];              \
        _Pragma("unroll") for (int mf = 0; mf < 4; ++mf)                                      \
            _Pragma("unroll") for (int nf = 0; nf < 4; ++nf)                                  \
                acc[mf][nf] = __builtin_amdgcn_mfma_f32_16x16x32_bf16(af[mf], bf[nf],         \
                                                                      acc[mf][nf], 0, 0, 0);  \
    }

#define KSTEP(KT, BUF, CUR, NXT, VMTOK, DOST)                        \
    {                                                                \
        __builtin_amdgcn_s_barrier();                                \
        if (DOST) ISSUE((KT) + 1, NXT);                              \
        asm volatile("s_waitcnt vmcnt(" VMTOK ")" ::: "memory");     \
        WRITEA(CUR, BUF, KT);                                        \
        __builtin_amdgcn_s_barrier();                                \
        asm volatile("" ::: "memory");                               \
        COMPUTE(BUF);                                                \
    }

    ISSUE(0, 0);

    for (int tt = 0; tt < 15; ++tt) {
        KSTEP(2 * tt + 0, 0, 0, 1, "6", true);
        KSTEP(2 * tt + 1, 1, 1, 0, "6", true);
    }
    KSTEP(30, 0, 0, 1, "6", true);
    KSTEP(31, 1, 1, 0, "0", false);

#undef KSTEP
#undef COMPUTE
#undef WRITEA
#undef ISSUE

    // ---- fused epilogue ----
    float s[4][4];
#pragma unroll
    for (int i = 0; i < 4; ++i)
#pragma unroll
        for (int j = 0; j < 4; ++j) s[i][j] = 0.f;

#pragma unroll
    for (int nf = 0; nf < 4; ++nf) {
        int e = e0 + E + nf * 16 + l15;
        float tv = t[b * ND + e];
        float wv = w_att[e];
#pragma unroll
        for (int mf = 0; mf < 4; ++mf)
#pragma unroll
            for (int r = 0; r < 4; ++r)
                s[mf][r] += fast_tanh(acc[mf][nf][r] + tv) * wv;
    }
#pragma unroll
    for (int mf = 0; mf < 4; ++mf)
#pragma unroll
        for (int r = 0; r < 4; ++r) {
            float v = s[mf][r];
            v += __shfl_xor(v, 1);
            v += __shfl_xor(v, 2);
            v += __shfl_xor(v, 4);
            v += __shfl_xor(v, 8);
            s[mf][r] = v;
        }
    if (l15 == 0) {
#pragma unroll
        for (int mf = 0; mf < 4; ++mf)
#pragma unroll
            for (int r = 0; r < 4; ++r)
                red[w][mf * 16 + kq4 * 4 + r] = s[mf][r];
    }
    __syncthreads();
    if (tid < 128) {
        int half = tid >> 6;
        int rl = tid & 63;
        float v = red[half * 2][rl] + red[half * 2 + 1][rl];
        spart[ct * 65536 + row0 + half * 64 + rl] = v;
    }
}

// ================= FALLBACK scores (round-3 verbatim, proven) =================
__global__ __launch_bounds__(512) void scores_mfma_kernel(const float* __restrict__ x,
                                                          const ushort* __restrict__ Wb,
                                                          const float* __restrict__ t,
                                                          const float* __restrict__ w_att,
                                                          float* __restrict__ scores) {
    __shared__ ushort As[2][64 * 256];
    __shared__ float red[8][64];

    int tid = threadIdx.x;
    int row0 = blockIdx.x * 64;
    int b = row0 >> 12;
    const float4* xf4 = (const float4*)x;

    int sr = tid >> 3;
    int sc = tid & 7;
    int swzbase = (sr & 7) << 3;

    float4 nx[8];
#pragma unroll
    for (int j = 0; j < 8; ++j)
        nx[j] = xf4[(size_t)(row0 + sr) * 256 + sc + j * 8];
#pragma unroll
    for (int j = 0; j < 8; ++j) {
        int c4 = sc + j * 8;
        ushort4 o;
        o.x = f2bf(nx[j].x); o.y = f2bf(nx[j].y); o.z = f2bf(nx[j].z); o.w = f2bf(nx[j].w);
        *(ushort4*)&As[0][sr * 256 + ((c4 * 4) ^ swzbase)] = o;
    }
    __syncthreads();

    int w = tid >> 6;
    int l = tid & 63;
    int l15 = l & 15;
    int kofs = (l >> 4) * 8;
    int xorv = (l & 7) << 3;
    int n0 = w * 128;

    v4f acc[2][4][4];
#pragma unroll
    for (int p = 0; p < 2; ++p)
#pragma unroll
        for (int i = 0; i < 4; ++i)
#pragma unroll
            for (int j = 0; j < 4; ++j) acc[p][i][j] = (v4f)(0.f);

    const ushort* bbase0 = Wb + (size_t)(n0 + l15) * ND + kofs;
    const ushort* bbase1 = bbase0 + (size_t)64 * ND;

#pragma unroll
    for (int kh = 0; kh < 4; ++kh) {
        if (kh < 3) {
#pragma unroll
            for (int j = 0; j < 8; ++j)
                nx[j] = xf4[(size_t)(row0 + sr) * 256 + (kh + 1) * 64 + sc + j * 8];
        }
        const ushort* Ab = &As[kh & 1][0];
        int kb = kh * 256;

        v8s b0c[4], b0n[4], b1[4];
#pragma unroll
        for (int nf = 0; nf < 4; ++nf) b0c[nf] = *(const v8s*)(bbase0 + (size_t)nf * 16 * ND + kb);

#pragma unroll
        for (int ks = 0; ks < 8; ++ks) {
            int kk = kb + ks * 32;
            int elem = (ks * 32 + kofs) ^ xorv;
            v8s af[4];
#pragma unroll
            for (int mf = 0; mf < 4; ++mf)
                af[mf] = *(const v8s*)&Ab[(mf * 16 + l15) * 256 + elem];
#pragma unroll
            for (int nf = 0; nf < 4; ++nf)
                b1[nf] = *(const v8s*)(bbase1 + (size_t)nf * 16 * ND + kk);
            if (ks < 7) {
#pragma unroll
                for (int nf = 0; nf < 4; ++nf)
                    b0n[nf] = *(const v8s*)(bbase0 + (size_t)nf * 16 * ND + kk + 32);
            }
#pragma unroll
            for (int mf = 0; mf < 4; ++mf)
#pragma unroll
                for (int nf = 0; nf < 4; ++nf)
                    acc[0][mf][nf] = __builtin_amdgcn_mfma_f32_16x16x32_bf16(
                        af[mf], b0c[nf], acc[0][mf][nf], 0, 0, 0);
#pragma unroll
            for (int mf = 0; mf < 4; ++mf)
#pragma unroll
                for (int nf = 0; nf < 4; ++nf)
                    acc[1][mf][nf] = __builtin_amdgcn_mfma_f32_16x16x32_bf16(
                        af[mf], b1[nf], acc[1][mf][nf], 0, 0, 0);
#pragma unroll
            for (int nf = 0; nf < 4; ++nf) b0c[nf] = b0n[nf];
        }

        if (kh < 3) {
#pragma unroll
            for (int j = 0; j < 8; ++j) {
                int c4 = sc + j * 8;
                ushort4 o;
                o.x = f2bf(nx[j].x); o.y = f2bf(nx[j].y); o.z = f2bf(nx[j].z); o.w = f2bf(nx[j].w);
                *(ushort4*)&As[(kh + 1) & 1][sr * 256 + ((c4 * 4) ^ swzbase)] = o;
            }
            __syncthreads();
        }
    }

    float s[4][4];
#pragma unroll
    for (int i = 0; i < 4; ++i)
#pragma unroll
        for (int j = 0; j < 4; ++j) s[i][j] = 0.f;

#pragma unroll
    for (int pass = 0; pass < 2; ++pass)
#pragma unroll
        for (int nf = 0; nf < 4; ++nf) {
            int e = n0 + pass * 64 + nf * 16 + l15;
            float tv = t[b * ND + e];
            float wv = w_att[e];
#pragma unroll
            for (int mf = 0; mf < 4; ++mf)
#pragma unroll
                for (int r = 0; r < 4; ++r)
                    s[mf][r] += fast_tanh(acc[pass][mf][nf][r] + tv) * wv;
        }

#pragma unroll
    for (int mf = 0; mf < 4; ++mf)
#pragma unroll
        for (int r = 0; r < 4; ++r) {
            float v = s[mf][r];
            v += __shfl_xor(v, 1);
            v += __shfl_xor(v, 2);
            v += __shfl_xor(v, 4);
            v += __shfl_xor(v, 8);
            s[mf][r] = v;
        }
    if (l15 == 0) {
#pragma unroll
        for (int mf = 0; mf < 4; ++mf)
#pragma unroll
            for (int r = 0; r < 4; ++r)
                red[w][mf * 16 + (l >> 4) * 4 + r] = s[mf][r];
    }
    __syncthreads();
    if (tid < 64) {
        float v = 0.f;
#pragma unroll
        for (int ww = 0; ww < 8; ++ww) v += red[ww][tid];
        scores[(size_t)b * NS + (row0 & (NS - 1)) + tid] = v;
    }
}

// ---------------- softmax (fast): sum 8 col-tile partials, then softmax ----------------
__global__ __launch_bounds__(256) void softmax8_kernel(const float* __restrict__ spart,
                                                       float* __restrict__ weights) {
    int b = blockIdx.x;
    int tid = threadIdx.x;
    float v[16];
    float lmax = -1e30f;
#pragma unroll
    for (int i = 0; i < 16; ++i) {
        int grow = b * NS + tid + i * 256;
        float sum = 0.f;
#pragma unroll
        for (int c = 0; c < 8; ++c) sum += spart[c * 65536 + grow];
        v[i] = sum;
        lmax = fmaxf(lmax, sum);
    }
#pragma unroll
    for (int off = 32; off >= 1; off >>= 1) lmax = fmaxf(lmax, __shfl_xor(lmax, off));
    __shared__ float redm[4];
    int wave = tid >> 6;
    if ((tid & 63) == 0) redm[wave] = lmax;
    __syncthreads();
    float bmax = fmaxf(fmaxf(redm[0], redm[1]), fmaxf(redm[2], redm[3]));

    float lsum = 0.f;
#pragma unroll
    for (int i = 0; i < 16; ++i) {
        v[i] = expf(v[i] - bmax);
        lsum += v[i];
    }
#pragma unroll
    for (int off = 32; off >= 1; off >>= 1) lsum += __shfl_xor(lsum, off);
    __shared__ float reds[4];
    if ((tid & 63) == 0) reds[wave] = lsum;
    __syncthreads();
    float inv = 1.0f / (reds[0] + reds[1] + reds[2] + reds[3]);
#pragma unroll
    for (int i = 0; i < 16; ++i) weights[b * NS + tid + i * 256] = v[i] * inv;
}

// ---------------- softmax (fallback): plain ----------------
__global__ __launch_bounds__(256) void softmax_kernel(const float* __restrict__ scores,
                                                      float* __restrict__ weights) {
    int b = blockIdx.x;
    int tid = threadIdx.x;
    float v[16];
    float lmax = -1e30f;
#pragma unroll
    for (int i = 0; i < 16; ++i) {
        v[i] = scores[b * NS + tid + i * 256];
        lmax = fmaxf(lmax, v[i]);
    }
#pragma unroll
    for (int off = 32; off >= 1; off >>= 1) lmax = fmaxf(lmax, __shfl_xor(lmax, off));
    __shared__ float redm[4];
    int wave = tid >> 6;
    if ((tid & 63) == 0) redm[wave] = lmax;
    __syncthreads();
    float bmax = fmaxf(fmaxf(redm[0], redm[1]), fmaxf(redm[2], redm[3]));

    float lsum = 0.f;
#pragma unroll
    for (int i = 0; i < 16; ++i) {
        v[i] = expf(v[i] - bmax);
        lsum += v[i];
    }
#pragma unroll
    for (int off = 32; off >= 1; off >>= 1) lsum += __shfl_xor(lsum, off);
    __shared__ float reds[4];
    if ((tid & 63) == 0) reds[wave] = lsum;
    __syncthreads();
    float inv = 1.0f / (reds[0] + reds[1] + reds[2] + reds[3]);
#pragma unroll
    for (int i = 0; i < 16; ++i) weights[b * NS + tid + i * 256] = v[i] * inv;
}

// ---------------- wsum fp32 (fallback) ----------------
__global__ __launch_bounds__(256) void wsum_kernel(const float* __restrict__ x,
                                                   const float* __restrict__ w,
                                                   float* __restrict__ part) {
    int sc = blockIdx.x, b = blockIdx.y;
    int d0 = threadIdx.x * 4;
    const float* xb = x + ((size_t)b * NS + sc * 128) * ND;
    const float* wb = w + b * NS + sc * 128;
    float4 acc = {0.f, 0.f, 0.f, 0.f};
    for (int ss = 0; ss < 128; ++ss) {
        float wv = wb[ss];
        float4 xv = *(const float4*)&xb[(size_t)ss * ND + d0];
        acc.x += wv * xv.x;
        acc.y += wv * xv.y;
        acc.z += wv * xv.z;
        acc.w += wv * xv.w;
    }
    *(float4*)&part[(size_t)(b * 32 + sc) * ND + d0] = acc;
}

// ---------------- wsum bf16 (fast; reads xbf side-written by scores) ----------------
__global__ __launch_bounds__(256) void wsum_bf_kernel(const ushort* __restrict__ xbf,
                                                      const float* __restrict__ w,
                                                      float* __restrict__ part) {
    int sc = blockIdx.x, b = blockIdx.y;
    int d0 = threadIdx.x * 4;
    const ushort* xb = xbf + ((size_t)b * NS + sc * 128) * ND;
    const float* wb = w + b * NS + sc * 128;
    float4 acc = {0.f, 0.f, 0.f, 0.f};
    for (int ss = 0; ss < 128; ++ss) {
        float wv = wb[ss];
        ushort4 xv = *(const ushort4*)&xb[(size_t)ss * ND + d0];
        acc.x += wv * bf2f(xv.x);
        acc.y += wv * bf2f(xv.y);
        acc.z += wv * bf2f(xv.z);
        acc.w += wv * bf2f(xv.w);
    }
    *(float4*)&part[(size_t)(b * 32 + sc) * ND + d0] = acc;
}

// ---------------- reduce partials -> out ----------------
__global__ __launch_bounds__(256) void reduce_kernel(const float* __restrict__ part,
                                                     float* __restrict__ out) {
    int b = blockIdx.x;
    int d0 = threadIdx.x * 4;
    float4 acc = {0.f, 0.f, 0.f, 0.f};
#pragma unroll
    for (int sc = 0; sc < 32; ++sc) {
        float4 v = *(const float4*)&part[(size_t)(b * 32 + sc) * ND + d0];
        acc.x += v.x;
        acc.y += v.y;
        acc.z += v.z;
        acc.w += v.w;
    }
    *(float4*)&out[b * ND + d0] = acc;
}

extern "C" void kernel_launch(void* const* d_in, const int* in_sizes, int n_in,
                              void* d_out, int out_size, void* d_ws, size_t ws_size,
                              hipStream_t stream) {
    const float* x       = (const float*)d_in[0];
    const float* context = (const float*)d_in[1];
    const float* W_in    = (const float*)d_in[2];
    const float* b_in    = (const float*)d_in[3];
    const float* W_ctx   = (const float*)d_in[4];
    const float* b_ctx   = (const float*)d_in[5];
    const float* w_att   = (const float*)d_in[6];
    // b_att (d_in[7]): softmax is shift-invariant; it cancels.

    float* ws      = (float*)d_ws;
    float* t       = ws + WS_T;
    float* scores  = ws + WS_SCORES;
    float* weights = ws + WS_WEIGHTS;
    ushort* wbf16  = (ushort*)(ws + WS_SHARED);
    ushort* xbf16  = (ushort*)(ws + WS_XBF16);
    float* spart   = ws + WS_SPART;              // fast: spart, then part overlay
    float* partfb  = ws + WS_SHARED;             // fallback: part overlays wbf16
    float* out     = (float*)d_out;

    bool fast = ws_size >= WS_NEED;

    convw_kernel<<<dim3(512), 256, 0, stream>>>(W_in, wbf16);
    tvec_kernel<<<dim3(16, NB), 256, 0, stream>>>(context, W_ctx, b_in, b_ctx, t);
    if (fast) {
        scores_tile_kernel<<<dim3(4096), 256, 0, stream>>>(x, wbf16, t, w_att, spart, xbf16);
        softmax8_kernel<<<dim3(NB), 256, 0, stream>>>(spart, weights);
        wsum_bf_kernel<<<dim3(32, NB), 256, 0, stream>>>(xbf16, weights, spart);
        reduce_kernel<<<dim3(NB), 256, 0, stream>>>(spart, out);
    } else {
        scores_mfma_kernel<<<dim3(NM / 64), 512, 0, stream>>>(x, wbf16, t, w_att, scores);
        softmax_kernel<<<dim3(NB), 256, 0, stream>>>(scores, weights);
        wsum_kernel<<<dim3(32, NB), 256, 0, stream>>>(x, weights, partfb);
        reduce_kernel<<<dim3(NB), 256, 0, stream>>>(partfb, out);
    }
}

// Round 17
// 270.294 us; speedup vs baseline: 1.3216x; 1.3216x over previous
//
#include <hip/hip_runtime.h>
#include <hip/hip_bf16.h>
#include <math.h>

#define NB 16
#define NS 4096
#define ND 1024
#define NM (NB * NS)

// workspace layout (float offsets) — constants kept from proven rounds
#define WS_T       0                            // 16*1024
#define WS_SCORES  16384                        // 16*4096 (fallback path)
#define WS_WEIGHTS (WS_SCORES + NB * NS)        // 16*4096
#define WS_SHARED  (WS_WEIGHTS + NB * NS)       // 2MB: wbf16 (convw->scores); fallback: part overlay
#define WS_XBF16   (WS_SHARED + 524288)         // (region unused by fast path)
#define WS_SPART   (WS_XBF16 + 33554432)        // 2MB: spart[8][65536] (scores->softmax) then part
#define WS_NEED    (((size_t)WS_SPART + 524288) * 4)

typedef short v8s __attribute__((ext_vector_type(8)));
typedef float v4f __attribute__((ext_vector_type(4)));
typedef unsigned short ushort;

#define G_AS __attribute__((address_space(1)))
#define L_AS __attribute__((address_space(3)))

__device__ __forceinline__ ushort f2bf(float f) {
    __hip_bfloat16 h = __float2bfloat16(f);
    return *reinterpret_cast<ushort*>(&h);
}

__device__ __forceinline__ float fast_tanh(float x) {
    float e = __expf(2.0f * x);
    return 1.0f - 2.0f / (e + 1.0f);
}

// ---------------- kernel 0: W_in fp32 -> bf16 ----------------
__global__ __launch_bounds__(256) void convw_kernel(const float* __restrict__ W,
                                                    ushort* __restrict__ Wb) {
    int flat = blockIdx.x * 256 + threadIdx.x;
#pragma unroll
    for (int j = 0; j < 2; ++j) {
        int idx = flat + j * 131072;
        float4 v = ((const float4*)W)[idx];
        ushort4 o;
        o.x = f2bf(v.x); o.y = f2bf(v.y); o.z = f2bf(v.z); o.w = f2bf(v.w);
        ((ushort4*)Wb)[idx] = o;
    }
}

// ---------------- kernel 1: t[b][e] = b_in[e]+b_ctx[e]+context[b].W_ctx[e] ----------------
__global__ __launch_bounds__(256) void tvec_kernel(const float* __restrict__ context,
                                                   const float* __restrict__ W_ctx,
                                                   const float* __restrict__ b_in,
                                                   const float* __restrict__ b_ctx,
                                                   float* __restrict__ t) {
    __shared__ float ctx[ND];
    int b = blockIdx.y;
    int tid = threadIdx.x;
    for (int i = tid; i < ND; i += 256) ctx[i] = context[b * ND + i];
    __syncthreads();
    int e = blockIdx.x * 64 + (tid >> 2);
    int kq = tid & 3;
    const float4* wr = (const float4*)(W_ctx + (size_t)e * ND + kq * 256);
    const float4* cr = (const float4*)(ctx + kq * 256);
    float acc = 0.f;
#pragma unroll 4
    for (int k = 0; k < 64; ++k) {
        float4 w = wr[k];
        float4 c = cr[k];
        acc += c.x * w.x + c.y * w.y + c.z * w.z + c.w * w.w;
    }
    acc += __shfl_xor(acc, 1);
    acc += __shfl_xor(acc, 2);
    if (kq == 0) t[b * ND + e] = acc + b_in[e] + b_ctx[e];
}

// ================= FAST scores: 128x128xBK32, 4 blocks/CU, T14 reg-staged A (no convx) =================
// 256 thr / 4 waves (2x2), per-wave 64x64, acc[4][4]=64 AGPR, __launch_bounds__(256,4).
// A: x fp32 -> regs (4 float4/thread/tile, double-buffered sets) -> cvt bf16 -> ds_write into the
// proven fragment-order LDS layout. B: gload_lds bf16 from Wb.
// Per step: barrier; issue(k+1) [6 VMEM]; vmcnt(6); cvt+ds_write A(k); lgkmcnt(0); barrier; compute(k).
__global__ __launch_bounds__(256, 4) void scores_tile_kernel(const float* __restrict__ x,
                                                             const ushort* __restrict__ Wb,
                                                             const float* __restrict__ t,
                                                             const float* __restrict__ w_att,
                                                             float* __restrict__ spart) {
    __shared__ ushort As[2][4096];   // 8 KB each: granule (row*4+kq)*8 ushorts
    __shared__ ushort Bs[2][4096];
    __shared__ float red[4][64];

    int tid = threadIdx.x;
    int o = blockIdx.x;              // 4096 blocks
    int rt = (o & 7) * 64 + (o >> 6);
    int ct = (o >> 3) & 7;
    int row0 = rt << 7;
    int e0 = ct << 7;
    int b = row0 >> 12;              // 128 | 4096

    int g0 = tid, g1 = tid + 256;
    const float* gxA0 = x + (size_t)(row0 + (tid >> 2)) * ND + (tid & 3) * 8;
    const float* gxA1 = gxA0 + (size_t)64 * ND;
    const ushort* gaB0 = Wb + (size_t)(e0 + (g0 >> 2)) * ND + (g0 & 3) * 8;
    const ushort* gaB1 = Wb + (size_t)(e0 + (g1 >> 2)) * ND + (g1 & 3) * 8;

    int w = tid >> 6, l = tid & 63;
    int l15 = l & 15, kq4 = l >> 4;
    int R = (w >> 1) * 64;
    int E = (w & 1) * 64;

    v4f acc[4][4];
#pragma unroll
    for (int i = 0; i < 4; ++i)
#pragma unroll
        for (int j = 0; j < 4; ++j) acc[i][j] = (v4f)(0.f);

    float4 ra[2][4];

#define ISSUE(KT, RS)                                                                               \
    {                                                                                               \
        ra[RS][0] = *(const float4*)(gxA0 + (KT) * 32);                                             \
        ra[RS][1] = *(const float4*)(gxA0 + (KT) * 32 + 4);                                         \
        ra[RS][2] = *(const float4*)(gxA1 + (KT) * 32);                                             \
        ra[RS][3] = *(const float4*)(gxA1 + (KT) * 32 + 4);                                         \
        __builtin_amdgcn_global_load_lds((const G_AS void*)(gaB0 + (KT) * 32),                      \
                                         (L_AS void*)&Bs[(KT) & 1][g0 * 8], 16, 0, 0);             \
        __builtin_amdgcn_global_load_lds((const G_AS void*)(gaB1 + (KT) * 32),                      \
                                         (L_AS void*)&Bs[(KT) & 1][g1 * 8], 16, 0, 0);             \
    }

#define WRITEA(RS, BUF)                                                                             \
    {                                                                                               \
        v8s w0, w1;                                                                                 \
        w0[0] = (short)f2bf(ra[RS][0].x); w0[1] = (short)f2bf(ra[RS][0].y);                         \
        w0[2] = (short)f2bf(ra[RS][0].z); w0[3] = (short)f2bf(ra[RS][0].w);                         \
        w0[4] = (short)f2bf(ra[RS][1].x); w0[5] = (short)f2bf(ra[RS][1].y);                         \
        w0[6] = (short)f2bf(ra[RS][1].z); w0[7] = (short)f2bf(ra[RS][1].w);                         \
        w1[0] = (short)f2bf(ra[RS][2].x); w1[1] = (short)f2bf(ra[RS][2].y);                         \
        w1[2] = (short)f2bf(ra[RS][2].z); w1[3] = (short)f2bf(ra[RS][2].w);                         \
        w1[4] = (short)f2bf(ra[RS][3].x); w1[5] = (short)f2bf(ra[RS][3].y);                         \
        w1[6] = (short)f2bf(ra[RS][3].z); w1[7] = (short)f2bf(ra[RS][3].w);                         \
        *(v8s*)&As[BUF][g0 * 8] = w0;                                                               \
        *(v8s*)&As[BUF][g1 * 8] = w1;                                                               \
        asm volatile("s_waitcnt lgkmcnt(0)" ::: "memory");                                          \
    }

#define COMPUTE(BUF)                                                                          \
    {                                                                                         \
        v8s af[4], bf[4];                                                                     \
        _Pragma("unroll") for (int mf = 0; mf < 4; ++mf)                                      \
            af[mf] = *(const v8s*)&As[BUF][((R + mf * 16 + l15) * 4 + kq4) * 8];              \
        _Pragma("unroll") for (int nf = 0; nf < 4; ++nf)                                      \
            bf[nf] = *(const v8s*)&Bs[BUF][((E + nf * 16 + l15) * 4 + kq4) * 8];              \
        _Pragma("unroll") for (int mf = 0; mf < 4; ++mf)                                      \
            _Pragma("unroll") for (int nf = 0; nf < 4; ++nf)                                  \
                acc[mf][nf] = __builtin_amdgcn_mfma_f32_16x16x32_bf16(af[mf], bf[nf],         \
                                                                      acc[mf][nf], 0, 0, 0);  \
    }

#define KSTEP(KT, BUF, CUR, NXT, VMTOK, DOST)                        \
    {                                                                \
        __builtin_amdgcn_s_barrier();                                \
        if (DOST) ISSUE((KT) + 1, NXT);                              \
        asm volatile("s_waitcnt vmcnt(" VMTOK ")" ::: "memory");     \
        WRITEA(CUR, BUF);                                            \
        __builtin_amdgcn_s_barrier();                                \
        asm volatile("" ::: "memory");                               \
        COMPUTE(BUF);                                                \
    }

    ISSUE(0, 0);

    for (int tt = 0; tt < 15; ++tt) {
        KSTEP(2 * tt + 0, 0, 0, 1, "6", true);
        KSTEP(2 * tt + 1, 1, 1, 0, "6", true);
    }
    KSTEP(30, 0, 0, 1, "6", true);
    KSTEP(31, 1, 1, 0, "0", false);

#undef KSTEP
#undef COMPUTE
#undef WRITEA
#undef ISSUE

    // ---- fused epilogue: tanh + dot(w_att), cross-wave pair-sum, spart write ----
    float s[4][4];
#pragma unroll
    for (int i = 0; i < 4; ++i)
#pragma unroll
        for (int j = 0; j < 4; ++j) s[i][j] = 0.f;

#pragma unroll
    for (int nf = 0; nf < 4; ++nf) {
        int e = e0 + E + nf * 16 + l15;
        float tv = t[b * ND + e];
        float wv = w_att[e];
#pragma unroll
        for (int mf = 0; mf < 4; ++mf)
#pragma unroll
            for (int r = 0; r < 4; ++r)
                s[mf][r] += fast_tanh(acc[mf][nf][r] + tv) * wv;
    }
#pragma unroll
    for (int mf = 0; mf < 4; ++mf)
#pragma unroll
        for (int r = 0; r < 4; ++r) {
            float v = s[mf][r];
            v += __shfl_xor(v, 1);
            v += __shfl_xor(v, 2);
            v += __shfl_xor(v, 4);
            v += __shfl_xor(v, 8);
            s[mf][r] = v;
        }
    if (l15 == 0) {
#pragma unroll
        for (int mf = 0; mf < 4; ++mf)
#pragma unroll
            for (int r = 0; r < 4; ++r)
                red[w][mf * 16 + kq4 * 4 + r] = s[mf][r];
    }
    __syncthreads();
    if (tid < 128) {
        int half = tid >> 6;
        int rl = tid & 63;
        float v = red[half * 2][rl] + red[half * 2 + 1][rl];
        spart[ct * 65536 + row0 + half * 64 + rl] = v;
    }
}

// ================= FALLBACK scores (round-3 verbatim, proven) =================
__global__ __launch_bounds__(512) void scores_mfma_kernel(const float* __restrict__ x,
                                                          const ushort* __restrict__ Wb,
                                                          const float* __restrict__ t,
                                                          const float* __restrict__ w_att,
                                                          float* __restrict__ scores) {
    __shared__ ushort As[2][64 * 256];
    __shared__ float red[8][64];

    int tid = threadIdx.x;
    int row0 = blockIdx.x * 64;
    int b = row0 >> 12;
    const float4* xf4 = (const float4*)x;

    int sr = tid >> 3;
    int sc = tid & 7;
    int swzbase = (sr & 7) << 3;

    float4 nx[8];
#pragma unroll
    for (int j = 0; j < 8; ++j)
        nx[j] = xf4[(size_t)(row0 + sr) * 256 + sc + j * 8];
#pragma unroll
    for (int j = 0; j < 8; ++j) {
        int c4 = sc + j * 8;
        ushort4 o;
        o.x = f2bf(nx[j].x); o.y = f2bf(nx[j].y); o.z = f2bf(nx[j].z); o.w = f2bf(nx[j].w);
        *(ushort4*)&As[0][sr * 256 + ((c4 * 4) ^ swzbase)] = o;
    }
    __syncthreads();

    int w = tid >> 6;
    int l = tid & 63;
    int l15 = l & 15;
    int kofs = (l >> 4) * 8;
    int xorv = (l & 7) << 3;
    int n0 = w * 128;

    v4f acc[2][4][4];
#pragma unroll
    for (int p = 0; p < 2; ++p)
#pragma unroll
        for (int i = 0; i < 4; ++i)
#pragma unroll
            for (int j = 0; j < 4; ++j) acc[p][i][j] = (v4f)(0.f);

    const ushort* bbase0 = Wb + (size_t)(n0 + l15) * ND + kofs;
    const ushort* bbase1 = bbase0 + (size_t)64 * ND;

#pragma unroll
    for (int kh = 0; kh < 4; ++kh) {
        if (kh < 3) {
#pragma unroll
            for (int j = 0; j < 8; ++j)
                nx[j] = xf4[(size_t)(row0 + sr) * 256 + (kh + 1) * 64 + sc + j * 8];
        }
        const ushort* Ab = &As[kh & 1][0];
        int kb = kh * 256;

        v8s b0c[4], b0n[4], b1[4];
#pragma unroll
        for (int nf = 0; nf < 4; ++nf) b0c[nf] = *(const v8s*)(bbase0 + (size_t)nf * 16 * ND + kb);

#pragma unroll
        for (int ks = 0; ks < 8; ++ks) {
            int kk = kb + ks * 32;
            int elem = (ks * 32 + kofs) ^ xorv;
            v8s af[4];
#pragma unroll
            for (int mf = 0; mf < 4; ++mf)
                af[mf] = *(const v8s*)&Ab[(mf * 16 + l15) * 256 + elem];
#pragma unroll
            for (int nf = 0; nf < 4; ++nf)
                b1[nf] = *(const v8s*)(bbase1 + (size_t)nf * 16 * ND + kk);
            if (ks < 7) {
#pragma unroll
                for (int nf = 0; nf < 4; ++nf)
                    b0n[nf] = *(const v8s*)(bbase0 + (size_t)nf * 16 * ND + kk + 32);
            }
#pragma unroll
            for (int mf = 0; mf < 4; ++mf)
#pragma unroll
                for (int nf = 0; nf < 4; ++nf)
                    acc[0][mf][nf] = __builtin_amdgcn_mfma_f32_16x16x32_bf16(
                        af[mf], b0c[nf], acc[0][mf][nf], 0, 0, 0);
#pragma unroll
            for (int mf = 0; mf < 4; ++mf)
#pragma unroll
                for (int nf = 0; nf < 4; ++nf)
                    acc[1][mf][nf] = __builtin_amdgcn_mfma_f32_16x16x32_bf16(
                        af[mf], b1[nf], acc[1][mf][nf], 0, 0, 0);
#pragma unroll
            for (int nf = 0; nf < 4; ++nf) b0c[nf] = b0n[nf];
        }

        if (kh < 3) {
#pragma unroll
            for (int j = 0; j < 8; ++j) {
                int c4 = sc + j * 8;
                ushort4 o;
                o.x = f2bf(nx[j].x); o.y = f2bf(nx[j].y); o.z = f2bf(nx[j].z); o.w = f2bf(nx[j].w);
                *(ushort4*)&As[(kh + 1) & 1][sr * 256 + ((c4 * 4) ^ swzbase)] = o;
            }
            __syncthreads();
        }
    }

    float s[4][4];
#pragma unroll
    for (int i = 0; i < 4; ++i)
#pragma unroll
        for (int j = 0; j < 4; ++j) s[i][j] = 0.f;

#pragma unroll
    for (int pass = 0; pass < 2; ++pass)
#pragma unroll
        for (int nf = 0; nf < 4; ++nf) {
            int e = n0 + pass * 64 + nf * 16 + l15;
            float tv = t[b * ND + e];
            float wv = w_att[e];
#pragma unroll
            for (int mf = 0; mf < 4; ++mf)
#pragma unroll
                for (int r = 0; r < 4; ++r)
                    s[mf][r] += fast_tanh(acc[pass][mf][nf][r] + tv) * wv;
        }

#pragma unroll
    for (int mf = 0; mf < 4; ++mf)
#pragma unroll
        for (int r = 0; r < 4; ++r) {
            float v = s[mf][r];
            v += __shfl_xor(v, 1);
            v += __shfl_xor(v, 2);
            v += __shfl_xor(v, 4);
            v += __shfl_xor(v, 8);
            s[mf][r] = v;
        }
    if (l15 == 0) {
#pragma unroll
        for (int mf = 0; mf < 4; ++mf)
#pragma unroll
            for (int r = 0; r < 4; ++r)
                red[w][mf * 16 + (l >> 4) * 4 + r] = s[mf][r];
    }
    __syncthreads();
    if (tid < 64) {
        float v = 0.f;
#pragma unroll
        for (int ww = 0; ww < 8; ++ww) v += red[ww][tid];
        scores[(size_t)b * NS + (row0 & (NS - 1)) + tid] = v;
    }
}

// ---------------- softmax (fast): sum 8 col-tile partials, then softmax ----------------
__global__ __launch_bounds__(256) void softmax8_kernel(const float* __restrict__ spart,
                                                       float* __restrict__ weights) {
    int b = blockIdx.x;
    int tid = threadIdx.x;
    float v[16];
    float lmax = -1e30f;
#pragma unroll
    for (int i = 0; i < 16; ++i) {
        int grow = b * NS + tid + i * 256;
        float sum = 0.f;
#pragma unroll
        for (int c = 0; c < 8; ++c) sum += spart[c * 65536 + grow];
        v[i] = sum;
        lmax = fmaxf(lmax, sum);
    }
#pragma unroll
    for (int off = 32; off >= 1; off >>= 1) lmax = fmaxf(lmax, __shfl_xor(lmax, off));
    __shared__ float redm[4];
    int wave = tid >> 6;
    if ((tid & 63) == 0) redm[wave] = lmax;
    __syncthreads();
    float bmax = fmaxf(fmaxf(redm[0], redm[1]), fmaxf(redm[2], redm[3]));

    float lsum = 0.f;
#pragma unroll
    for (int i = 0; i < 16; ++i) {
        v[i] = expf(v[i] - bmax);
        lsum += v[i];
    }
#pragma unroll
    for (int off = 32; off >= 1; off >>= 1) lsum += __shfl_xor(lsum, off);
    __shared__ float reds[4];
    if ((tid & 63) == 0) reds[wave] = lsum;
    __syncthreads();
    float inv = 1.0f / (reds[0] + reds[1] + reds[2] + reds[3]);
#pragma unroll
    for (int i = 0; i < 16; ++i) weights[b * NS + tid + i * 256] = v[i] * inv;
}

// ---------------- softmax (fallback): plain ----------------
__global__ __launch_bounds__(256) void softmax_kernel(const float* __restrict__ scores,
                                                      float* __restrict__ weights) {
    int b = blockIdx.x;
    int tid = threadIdx.x;
    float v[16];
    float lmax = -1e30f;
#pragma unroll
    for (int i = 0; i < 16; ++i) {
        v[i] = scores[b * NS + tid + i * 256];
        lmax = fmaxf(lmax, v[i]);
    }
#pragma unroll
    for (int off = 32; off >= 1; off >>= 1) lmax = fmaxf(lmax, __shfl_xor(lmax, off));
    __shared__ float redm[4];
    int wave = tid >> 6;
    if ((tid & 63) == 0) redm[wave] = lmax;
    __syncthreads();
    float bmax = fmaxf(fmaxf(redm[0], redm[1]), fmaxf(redm[2], redm[3]));

    float lsum = 0.f;
#pragma unroll
    for (int i = 0; i < 16; ++i) {
        v[i] = expf(v[i] - bmax);
        lsum += v[i];
    }
#pragma unroll
    for (int off = 32; off >= 1; off >>= 1) lsum += __shfl_xor(lsum, off);
    __shared__ float reds[4];
    if ((tid & 63) == 0) reds[wave] = lsum;
    __syncthreads();
    float inv = 1.0f / (reds[0] + reds[1] + reds[2] + reds[3]);
#pragma unroll
    for (int i = 0; i < 16; ++i) weights[b * NS + tid + i * 256] = v[i] * inv;
}

// ---------------- wsum (fp32 x, proven; at HBM roofline) ----------------
__global__ __launch_bounds__(256) void wsum_kernel(const float* __restrict__ x,
                                                   const float* __restrict__ w,
                                                   float* __restrict__ part) {
    int sc = blockIdx.x, b = blockIdx.y;
    int d0 = threadIdx.x * 4;
    const float* xb = x + ((size_t)b * NS + sc * 128) * ND;
    const float* wb = w + b * NS + sc * 128;
    float4 acc = {0.f, 0.f, 0.f, 0.f};
    for (int ss = 0; ss < 128; ++ss) {
        float wv = wb[ss];
        float4 xv = *(const float4*)&xb[(size_t)ss * ND + d0];
        acc.x += wv * xv.x;
        acc.y += wv * xv.y;
        acc.z += wv * xv.z;
        acc.w += wv * xv.w;
    }
    *(float4*)&part[(size_t)(b * 32 + sc) * ND + d0] = acc;
}

// ---------------- reduce partials -> out ----------------
__global__ __launch_bounds__(256) void reduce_kernel(const float* __restrict__ part,
                                                     float* __restrict__ out) {
    int b = blockIdx.x;
    int d0 = threadIdx.x * 4;
    float4 acc = {0.f, 0.f, 0.f, 0.f};
#pragma unroll
    for (int sc = 0; sc < 32; ++sc) {
        float4 v = *(const float4*)&part[(size_t)(b * 32 + sc) * ND + d0];
        acc.x += v.x;
        acc.y += v.y;
        acc.z += v.z;
        acc.w += v.w;
    }
    *(float4*)&out[b * ND + d0] = acc;
}

extern "C" void kernel_launch(void* const* d_in, const int* in_sizes, int n_in,
                              void* d_out, int out_size, void* d_ws, size_t ws_size,
                              hipStream_t stream) {
    const float* x       = (const float*)d_in[0];
    const float* context = (const float*)d_in[1];
    const float* W_in    = (const float*)d_in[2];
    const float* b_in    = (const float*)d_in[3];
    const float* W_ctx   = (const float*)d_in[4];
    const float* b_ctx   = (const float*)d_in[5];
    const float* w_att   = (const float*)d_in[6];
    // b_att (d_in[7]): softmax is shift-invariant; it cancels.

    float* ws      = (float*)d_ws;
    float* t       = ws + WS_T;
    float* scores  = ws + WS_SCORES;
    float* weights = ws + WS_WEIGHTS;
    ushort* wbf16  = (ushort*)(ws + WS_SHARED);
    float* spart   = ws + WS_SPART;              // fast: spart, then part overlay
    float* partfb  = ws + WS_SHARED;             // fallback: part overlays wbf16
    float* out     = (float*)d_out;

    bool fast = ws_size >= WS_NEED;

    convw_kernel<<<dim3(512), 256, 0, stream>>>(W_in, wbf16);
    tvec_kernel<<<dim3(16, NB), 256, 0, stream>>>(context, W_ctx, b_in, b_ctx, t);
    if (fast) {
        scores_tile_kernel<<<dim3(4096), 256, 0, stream>>>(x, wbf16, t, w_att, spart);
        softmax8_kernel<<<dim3(NB), 256, 0, stream>>>(spart, weights);
        wsum_kernel<<<dim3(32, NB), 256, 0, stream>>>(x, weights, spart);
        reduce_kernel<<<dim3(NB), 256, 0, stream>>>(spart, out);
    } else {
        scores_mfma_kernel<<<dim3(NM / 64), 512, 0, stream>>>(x, wbf16, t, w_att, scores);
        softmax_kernel<<<dim3(NB), 256, 0, stream>>>(scores, weights);
        wsum_kernel<<<dim3(32, NB), 256, 0, stream>>>(x, weights, partfb);
        reduce_kernel<<<dim3(NB), 256, 0, stream>>>(partfb, out);
    }
}